// Round 1
// baseline (7641.271 us; speedup 1.0000x reference)
//
#include <hip/hip_runtime.h>
#include <cstdint>
#include <cstddef>

#define Dk 256
#define Hk 512
#define Bk 16
#define Tk 512
#define Gk 2048      // 4H
#define NVk 262144   // H*H

typedef __bf16 bf16;
typedef __bf16 bf16x8 __attribute__((ext_vector_type(8)));
typedef float  f32x4  __attribute__((ext_vector_type(4)));

// ---------- prep kernels ----------
__global__ __launch_bounds__(256) void cvt_f32_bf16(const float* __restrict__ in,
                                                    bf16* __restrict__ out, int n8) {
  int i = blockIdx.x * 256 + threadIdx.x;
  if (i >= n8) return;
  const float4* p = reinterpret_cast<const float4*>(in) + (size_t)i * 2;
  float4 a = p[0], b = p[1];
  bf16x8 v;
  v[0] = (bf16)a.x; v[1] = (bf16)a.y; v[2] = (bf16)a.z; v[3] = (bf16)a.w;
  v[4] = (bf16)b.x; v[5] = (bf16)b.y; v[6] = (bf16)b.z; v[7] = (bf16)b.w;
  *reinterpret_cast<bf16x8*>(out + (size_t)i * 8) = v;
}

// V_w[j][d*512+h'] (fp32) -> packed B: V2p[(d/8)][n=(j,h')][d%8] (bf16)
__global__ __launch_bounds__(256) void pack_V(const float* __restrict__ Vw,
                                              bf16* __restrict__ V2p) {
  int n = blockIdx.x * 256 + threadIdx.x;        // 0..262143
  int j = n >> 9, hp = n & 511;
  const float* src = Vw + (size_t)j * 131072 + hp;
  for (int kb = 0; kb < 32; ++kb) {
    bf16x8 v;
#pragma unroll
    for (int r = 0; r < 8; ++r) v[r] = (bf16)src[(size_t)(kb * 8 + r) * 512];
    *reinterpret_cast<bf16x8*>(V2p + ((size_t)kb * NVk + n) * 8) = v;
  }
}

// W_w[g][d] (fp32) -> packed B: Wp[(d/8)][g][d%8] (bf16)
__global__ __launch_bounds__(256) void pack_W(const float* __restrict__ Ww,
                                              bf16* __restrict__ Wp) {
  int g = blockIdx.x * 256 + threadIdx.x;        // 0..2047
  const float* src = Ww + (size_t)g * 256;
  for (int kb = 0; kb < 32; ++kb) {
    bf16x8 v;
#pragma unroll
    for (int r = 0; r < 8; ++r) v[r] = (bf16)src[kb * 8 + r];
    *reinterpret_cast<bf16x8*>(Wp + ((size_t)kb * Gk + g) * 8) = v;
  }
}

__global__ __launch_bounds__(256) void init_state(float* __restrict__ hbuf,
                                                  float* __restrict__ cws) {
  int i = blockIdx.x * 256 + threadIdx.x;
  if (i < 16384) hbuf[i] = 0.f;
  if (i < 8192)  cws[i]  = 0.f;
}

// ---------- 128x128 tile MFMA GEMM:  out[m][n] = sum_k A[xrow(m)][k] * B[k][n] ----------
// A: x_bf row-major [*][256] bf16 ; B packed [k/8][N][k%8] bf16
// row map: b = m>>tcShift ; xrow = b*512 + t0 + (m & tcMask)
template <bool BF16_OUT>
__global__ __launch_bounds__(256) void gemm128(const bf16* __restrict__ Axk,
                                               const bf16* __restrict__ Bp,
                                               float* __restrict__ outF,
                                               bf16* __restrict__ outB,
                                               const float* __restrict__ bias,
                                               int N, int t0, int tcMask, int tcShift) {
  __shared__ uint4 a_sm[512];   // [kb(4)][m(128)] 16B each
  __shared__ uint4 b_sm[512];   // [kb(4)][n(128)]
  int tid = threadIdx.x;
  int lane = tid & 63, wid = tid >> 6;
  int quad = lane >> 4, l15 = lane & 15;
  int wm = wid >> 1, wn = wid & 1;
  int m0 = blockIdx.x * 128, n0 = blockIdx.y * 128;

  f32x4 acc[4][4];
#pragma unroll
  for (int i = 0; i < 4; ++i)
#pragma unroll
    for (int j = 0; j < 4; ++j) acc[i][j] = (f32x4){0.f, 0.f, 0.f, 0.f};

  int mA = tid >> 2, kbA = tid & 3;        // A staging: rows mA and mA+64
  int gm0 = m0 + mA, gm1 = gm0 + 64;
  size_t xrow0 = (size_t)(((gm0 >> tcShift) << 9) + t0 + (gm0 & tcMask));
  size_t xrow1 = (size_t)(((gm1 >> tcShift) << 9) + t0 + (gm1 & tcMask));
  int kbB = tid >> 6, nB = tid & 63;       // B staging: cols nB and nB+64

  const bf16x8* aptr = reinterpret_cast<const bf16x8*>(a_sm);
  const bf16x8* bptr = reinterpret_cast<const bf16x8*>(b_sm);

  for (int kk = 0; kk < 8; ++kk) {
    int k0 = kk * 32;
    a_sm[kbA * 128 + mA] =
        *reinterpret_cast<const uint4*>(Axk + xrow0 * 256 + k0 + kbA * 8);
    a_sm[kbA * 128 + mA + 64] =
        *reinterpret_cast<const uint4*>(Axk + xrow1 * 256 + k0 + kbA * 8);
    size_t kbg = (size_t)(kk * 4 + kbB);
    b_sm[kbB * 128 + nB] =
        *reinterpret_cast<const uint4*>(Bp + (kbg * N + n0 + nB) * 8);
    b_sm[kbB * 128 + nB + 64] =
        *reinterpret_cast<const uint4*>(Bp + (kbg * N + n0 + nB + 64) * 8);
    __syncthreads();
    bf16x8 af[4], bfr[4];
#pragma unroll
    for (int i = 0; i < 4; ++i) af[i]  = aptr[quad * 128 + wm * 64 + i * 16 + l15];
#pragma unroll
    for (int j = 0; j < 4; ++j) bfr[j] = bptr[quad * 128 + wn * 64 + j * 16 + l15];
#pragma unroll
    for (int i = 0; i < 4; ++i)
#pragma unroll
      for (int j = 0; j < 4; ++j)
        acc[i][j] = __builtin_amdgcn_mfma_f32_16x16x32_bf16(af[i], bfr[j], acc[i][j], 0, 0, 0);
    __syncthreads();
  }

#pragma unroll
  for (int i = 0; i < 4; ++i) {
    int row = m0 + wm * 64 + i * 16 + quad * 4;
#pragma unroll
    for (int j = 0; j < 4; ++j) {
      int col = n0 + wn * 64 + j * 16 + l15;
      f32x4 v = acc[i][j];
      if (BF16_OUT) {
#pragma unroll
        for (int r = 0; r < 4; ++r)
          outB[(size_t)(row + r) * N + col] = (bf16)v[r];
      } else {
        float bv = bias[col];
#pragma unroll
        for (int r = 0; r < 4; ++r)
          outF[(size_t)(row + r) * N + col] = v[r] + bv;
      }
    }
  }
}

// ---------- one scan timestep ----------
// grid 512 blocks (one j each), 256 threads.
__global__ __launch_bounds__(256) void scan_step(const bf16* __restrict__ At, size_t bStride,
                                                 const bf16* __restrict__ Ubf,
                                                 const float* __restrict__ wx,
                                                 const float* __restrict__ Ub,
                                                 const float* __restrict__ Vb,
                                                 float* __restrict__ hbuf,
                                                 float* __restrict__ cws,
                                                 float* __restrict__ out, int t) {
  __shared__ float h_s[16 * 512];
  __shared__ float gate_s[64];
  __shared__ float m_s[16];
  int tid = threadIdx.x;
  int j = blockIdx.x;
  const float* hprev = hbuf + (t & 1) * 8192;
  float* hnext = hbuf + ((t + 1) & 1) * 8192;

  const float4* hp4 = reinterpret_cast<const float4*>(hprev);
  float4* hs4 = reinterpret_cast<float4*>(h_s);
#pragma unroll
  for (int i = 0; i < 8; ++i) hs4[tid + i * 256] = hp4[tid + i * 256];
  __syncthreads();

  // gates: 64 values (16 b x 4 q), 4 threads each over h'
  {
    int gv = tid >> 2, s4 = tid & 3;
    int b = gv >> 2, q = gv & 3;
    int g = q * 512 + j;
    const bf16* Ur = Ubf + (size_t)g * 512;
    const float* hb = h_s + b * 512;
    float acc = 0.f;
#pragma unroll
    for (int i = 0; i < 16; ++i) {
      int off = (i * 4 + s4) * 8;
      bf16x8 uv = *reinterpret_cast<const bf16x8*>(Ur + off);
      float4 h0 = *reinterpret_cast<const float4*>(hb + off);
      float4 h1 = *reinterpret_cast<const float4*>(hb + off + 4);
      acc += (float)uv[0] * h0.x + (float)uv[1] * h0.y + (float)uv[2] * h0.z + (float)uv[3] * h0.w
           + (float)uv[4] * h1.x + (float)uv[5] * h1.y + (float)uv[6] * h1.z + (float)uv[7] * h1.w;
    }
    acc += __shfl_xor(acc, 1);
    acc += __shfl_xor(acc, 2);
    if (s4 == 0) gate_s[gv] = acc + wx[(size_t)(b * Tk + t) * Gk + g] + Ub[g];
  }
  // m: 16 values (one per b), 16 threads each over h'
  {
    int b = tid >> 4, s = tid & 15;
    const bf16* Ar = At + (size_t)b * bStride + (size_t)j * 512;
    const float* hb = h_s + b * 512;
    float acc = 0.f;
#pragma unroll
    for (int i = 0; i < 4; ++i) {
      int off = (i * 16 + s) * 8;
      bf16x8 av = *reinterpret_cast<const bf16x8*>(Ar + off);
      float4 h0 = *reinterpret_cast<const float4*>(hb + off);
      float4 h1 = *reinterpret_cast<const float4*>(hb + off + 4);
      acc += (float)av[0] * h0.x + (float)av[1] * h0.y + (float)av[2] * h0.z + (float)av[3] * h0.w
           + (float)av[4] * h1.x + (float)av[5] * h1.y + (float)av[6] * h1.z + (float)av[7] * h1.w;
    }
    acc += __shfl_xor(acc, 1);
    acc += __shfl_xor(acc, 2);
    acc += __shfl_xor(acc, 4);
    acc += __shfl_xor(acc, 8);
    if (s == 0) m_s[b] = acc;
  }
  __syncthreads();
  if (tid < 16) {
    int b = tid;
    float gi = gate_s[b * 4 + 0], gf = gate_s[b * 4 + 1];
    float go = gate_s[b * 4 + 2], gg = gate_s[b * 4 + 3];
    float iv = 1.f / (1.f + __expf(-gi));
    float fv = 1.f / (1.f + __expf(-gf));
    float ov = 1.f / (1.f + __expf(-go));
    float gv = tanhf(gg);
    float mv = tanhf(m_s[b] + Vb[j]);
    int idx = b * 512 + j;
    float c = fv * cws[idx] + iv * gv + 0.1f * mv;
    cws[idx] = c;
    float h = ov * tanhf(c);
    hnext[idx] = h;
    out[(size_t)(b * Tk + t) * Hk + j] = h;
    if (t == Tk - 1) {
      out[(size_t)4194304 + idx] = h;          // hT
      out[(size_t)4194304 + 8192 + idx] = c;   // cT
    }
  }
}

// ---------- host ----------
extern "C" void kernel_launch(void* const* d_in, const int* in_sizes, int n_in,
                              void* d_out, int out_size, void* d_ws, size_t ws_size,
                              hipStream_t stream) {
  const float* x  = (const float*)d_in[0];
  const float* Ww = (const float*)d_in[1];
  const float* Wb = (const float*)d_in[2];
  const float* Uw = (const float*)d_in[3];
  const float* Ub = (const float*)d_in[4];
  const float* Vw = (const float*)d_in[5];
  const float* Vb = (const float*)d_in[6];
  float* out = (float*)d_out;

  char* ws = (char*)d_ws;
  size_t off = 0;
  auto alloc = [&](size_t bytes) -> void* {
    void* p = ws + off;
    off = (off + bytes + 255) & ~(size_t)255;
    return p;
  };
  bf16*  x_bf = (bf16*)alloc((size_t)Bk * Tk * Dk * 2);   //   4 MB
  bf16*  V2p  = (bf16*)alloc((size_t)32 * NVk * 8 * 2);   // 134 MB
  bf16*  Wp   = (bf16*)alloc((size_t)32 * Gk * 8 * 2);    //   1 MB
  bf16*  Ubf  = (bf16*)alloc((size_t)Gk * Hk * 2);        //   2 MB
  float* wx   = (float*)alloc((size_t)Bk * Tk * Gk * 4);  //  67 MB
  float* hbuf = (float*)alloc((size_t)16384 * 4);
  float* cws  = (float*)alloc((size_t)8192 * 4);
  size_t fixedBytes = off;

  int Tc = 512;   // time-chunk for A; shrink until it fits the workspace
  while (Tc > 8 && fixedBytes + (size_t)Bk * Tc * Hk * Hk * 2 > ws_size) Tc >>= 1;
  bf16* A_ws = (bf16*)alloc((size_t)Bk * Tc * Hk * Hk * 2);
  int tcShift = 31 - __builtin_clz((unsigned)Tc);

  cvt_f32_bf16<<<1024, 256, 0, stream>>>(x, x_bf, 262144);   // 2,097,152 / 8
  cvt_f32_bf16<<<512, 256, 0, stream>>>(Uw, Ubf, 131072);    // 1,048,576 / 8
  pack_V<<<1024, 256, 0, stream>>>(Vw, V2p);
  pack_W<<<8, 256, 0, stream>>>(Ww, Wp);
  init_state<<<64, 256, 0, stream>>>(hbuf, cws);

  // wx = x @ W^T + W_b   (M=8192, N=2048, K=256), identity row map
  gemm128<false><<<dim3(64, 16), 256, 0, stream>>>(x_bf, Wp, wx, nullptr, Wb,
                                                   Gk, 0, 511, 9);

  for (int c0 = 0; c0 < Tk; c0 += Tc) {
    // A[b, t0..t0+Tc, j, h'] = x(b,t) . V(:,d,:)   (M=16*Tc, N=262144, K=256)
    gemm128<true><<<dim3(Bk * Tc / 128, NVk / 128), 256, 0, stream>>>(
        x_bf, V2p, nullptr, A_ws, nullptr, NVk, c0, Tc - 1, tcShift);
    for (int t = c0; t < c0 + Tc; ++t) {
      scan_step<<<512, 256, 0, stream>>>(A_ws + (size_t)(t - c0) * NVk,
                                         (size_t)Tc * NVk, Ubf, wx, Ub, Vb,
                                         hbuf, cws, out, t);
    }
  }
}